// Round 2
// baseline (162.871 us; speedup 1.0000x reference)
//
#include <hip/hip_runtime.h>
#include <math.h>

#define B_DIM 4096
#define T_DIM 1024
#define NCLS  3

#define TB 64              // timesteps per block
#define BB 64              // batch rows per block
#define NT (T_DIM / TB)    // 16 t-chunks
#define NB (B_DIM / BB)    // 64 b-chunks
#define THREADS 256

// ln Gamma(x), x >= 1 here. Shift to x>=8, then Stirling series.
__device__ __forceinline__ float lgf(float x) {
    float p = 1.0f;
    while (x < 8.0f) { p *= x; x += 1.0f; }
    float inv  = 1.0f / x;
    float inv2 = inv * inv;
    float s = (x - 0.5f) * __logf(x) - x + 0.91893853320467274f
            + inv * (0.083333333333333f
                     - inv2 * (0.0027777777777778f - inv2 * 0.00079365079365f));
    return s - __logf(p);
}

// digamma(x), x >= 1 here. Shift to x>=6, asymptotic series.
__device__ __forceinline__ float digf(float x) {
    float r = 0.0f;
    while (x < 6.0f) { r -= 1.0f / x; x += 1.0f; }
    float inv  = 1.0f / x;
    float inv2 = inv * inv;
    return r + __logf(x) - 0.5f * inv
         - inv2 * (0.083333333333333f
                   - inv2 * (0.0083333333333333f - inv2 * 0.0039682539682540f));
}

__global__ void kl_zero(float* ws) {
    int i = blockIdx.x * 256 + threadIdx.x;
    if (i < T_DIM * NCLS * 2) ws[i] = 0.0f;
}

__global__ __launch_bounds__(THREADS)
void kl_partial(const float* __restrict__ logits,
                const float* __restrict__ targets,
                float* __restrict__ gcnt,
                float* __restrict__ gksum) {
    __shared__ float lcnt[TB * NCLS];
    __shared__ float lksum[TB * NCLS];

    const int tchunk = blockIdx.x % NT;
    const int bchunk = blockIdx.x / NT;
    const int t0 = tchunk * TB;
    const int b0 = bchunk * BB;

    for (int i = threadIdx.x; i < TB * NCLS; i += THREADS) {
        lcnt[i] = 0.0f; lksum[i] = 0.0f;
    }
    __syncthreads();

    const int lt4 = (threadIdx.x & 15) * 4;  // 0..60, group of 4 timesteps
    const int lbb = threadIdx.x >> 4;        // 0..15

    for (int it = 0; it < BB / 16; ++it) {   // 4 iterations
        const int b = b0 + it * 16 + lbb;
        const int t = t0 + lt4;
        const size_t row = (size_t)b * T_DIM + t;

        const float4* tg = (const float4*)(targets + row * 3);
        float4 tg0 = tg[0], tg1 = tg[1], tg2 = tg[2];
        const float4* lg = (const float4*)(logits + row * 2);
        float4 lg0 = lg[0], lg1 = lg[1];

        float tw_[4] = {tg0.x, tg0.w, tg1.z, tg2.y};
        float tc_[4] = {tg0.y, tg1.x, tg1.w, tg2.z};
        float dx_[4] = {tg0.z, tg1.y, tg2.x, tg2.w};
        float l0_[4] = {lg0.x, lg0.z, lg1.x, lg1.z};
        float l1_[4] = {lg0.y, lg0.w, lg1.y, lg1.w};

#pragma unroll
        for (int r = 0; r < 4; ++r) {
            float twv = tw_[r], tcv = tc_[r], dxv = dx_[r];
            // valid iff all three > -inf (padding sets all to -inf)
            if (!(twv > -INFINITY && tcv > -INFINITY && dxv > -INFINITY)) continue;
            int c = (int)dxv;

            float pwv = 1.0f / (1.0f + __expf(-l0_[r]));
            float pcv = (1.0f / (1.0f + __expf(-l1_[r]))) * (float)(T_DIM - 1) + 5.0f;

            float ta = tcv * twv + 1.0f;
            float tbv = tcv * (1.0f - twv) + 1.0f;
            float pa = pcv * pwv + 1.0f;
            float pb = pcv * (1.0f - pwv) + 1.0f;
            float sp = ta + tbv;   // = tc + 2
            float sq = pa + pb;    // = pc + 2

            // KL( Beta(ta,tb) || Beta(pa,pb) )
            float kl = lgf(pa) + lgf(pb) + lgf(sp)
                     - lgf(ta) - lgf(tbv) - lgf(sq)
                     + (ta - pa) * digf(ta)
                     + (tbv - pb) * digf(tbv)
                     + (sq - sp) * digf(sp);

            int li = (lt4 + r) * NCLS + c;
            atomicAdd(&lksum[li], kl);
            atomicAdd(&lcnt[li], 1.0f);
        }
    }
    __syncthreads();

    for (int i = threadIdx.x; i < TB * NCLS; i += THREADS) {
        float cv = lcnt[i];
        if (cv != 0.0f) {
            atomicAdd(&gcnt[t0 * NCLS + i], cv);
            atomicAdd(&gksum[t0 * NCLS + i], lksum[i]);
        }
    }
}

__global__ void kl_final(const float* __restrict__ gcnt,
                         const float* __restrict__ gksum,
                         float* __restrict__ out) {
    __shared__ float red[256];
    float s = 0.0f;
    for (int i = threadIdx.x; i < T_DIM * NCLS; i += 256) {
        float cv = gcnt[i];
        if (cv > 0.0f) s += gksum[i] / cv;
    }
    red[threadIdx.x] = s;
    __syncthreads();
    for (int off = 128; off > 0; off >>= 1) {
        if ((int)threadIdx.x < off) red[threadIdx.x] += red[threadIdx.x + off];
        __syncthreads();
    }
    if (threadIdx.x == 0) out[0] = red[0] / (float)(NCLS * T_DIM);
}

extern "C" void kernel_launch(void* const* d_in, const int* in_sizes, int n_in,
                              void* d_out, int out_size, void* d_ws, size_t ws_size,
                              hipStream_t stream) {
    const float* logits  = (const float*)d_in[0];  // [B,T,2] f32
    const float* targets = (const float*)d_in[1];  // [B,T,3] f32
    float* gcnt  = (float*)d_ws;                   // [T*3]
    float* gksum = gcnt + T_DIM * NCLS;            // [T*3]
    float* out   = (float*)d_out;

    kl_zero<<<(T_DIM * NCLS * 2 + 255) / 256, 256, 0, stream>>>((float*)d_ws);
    kl_partial<<<NT * NB, THREADS, 0, stream>>>(logits, targets, gcnt, gksum);
    kl_final<<<1, 256, 0, stream>>>(gcnt, gksum, out);
}

// Round 3
// 138.760 us; speedup vs baseline: 1.1738x; 1.1738x over previous
//
#include <hip/hip_runtime.h>
#include <math.h>

#define B_DIM 4096
#define T_DIM 1024
#define NCLS  3

#define TB 64              // timesteps per block
#define BB 32              // batch rows per block
#define NT (T_DIM / TB)    // 16 t-chunks
#define NB (B_DIM / BB)    // 128 b-chunks -> 2048 blocks
#define THREADS 256

__device__ __forceinline__ float rcpf(float x) { return __builtin_amdgcn_rcpf(x); }

// lgamma(y) for y >= 2, given lny = ln(y), u = 1/y. Stirling, err <~5e-6 at y=2.
__device__ __forceinline__ float stirl(float y, float lny, float u) {
    float u2 = u * u;
    float s = u * (0.083333333333333f
                   + u2 * (-0.0027777777777778f + u2 * 0.00079365079365f));
    return (y - 0.5f) * lny - y + 0.91893853320467274f + s;
}

// digamma(y) for y >= 3, given lny, u = 1/y. err <~1e-6 at y=3.
__device__ __forceinline__ float digam(float lny, float u) {
    float u2 = u * u;
    return lny - 0.5f * u
         - u2 * (0.083333333333333f
                 - u2 * (0.0083333333333333f - u2 * 0.0039682539682540f));
}

__global__ void kl_zero(float* ws) {
    int i = blockIdx.x * 256 + threadIdx.x;
    if (i < T_DIM * NCLS * 2) ws[i] = 0.0f;
}

__global__ __launch_bounds__(THREADS)
void kl_partial(const float* __restrict__ logits,
                const float* __restrict__ targets,
                float* __restrict__ gcnt,
                float* __restrict__ gksum) {
    __shared__ float lcnt[TB * NCLS];
    __shared__ float lksum[TB * NCLS];

    const int tchunk = blockIdx.x % NT;
    const int bchunk = blockIdx.x / NT;
    const int t0 = tchunk * TB;
    const int b0 = bchunk * BB;

    for (int i = threadIdx.x; i < TB * NCLS; i += THREADS) {
        lcnt[i] = 0.0f; lksum[i] = 0.0f;
    }
    __syncthreads();

    const int lt4 = (threadIdx.x & 15) * 4;  // 0..60: group of 4 timesteps
    const int lbb = threadIdx.x >> 4;        // 0..15

    for (int it = 0; it < BB / 16; ++it) {   // 2 iterations
        const int b = b0 + it * 16 + lbb;
        const int t = t0 + lt4;
        const size_t row = (size_t)b * T_DIM + t;

        const float4* tg = (const float4*)(targets + row * 3);
        float4 tg0 = tg[0], tg1 = tg[1], tg2 = tg[2];
        const float4* lg = (const float4*)(logits + row * 2);
        float4 lg0 = lg[0], lg1 = lg[1];

        float tw_[4] = {tg0.x, tg0.w, tg1.z, tg2.y};
        float tc_[4] = {tg0.y, tg1.x, tg1.w, tg2.z};
        float dx_[4] = {tg0.z, tg1.y, tg2.x, tg2.w};
        float l0_[4] = {lg0.x, lg0.z, lg1.x, lg1.z};
        float l1_[4] = {lg0.y, lg0.w, lg1.y, lg1.w};

#pragma unroll
        for (int r = 0; r < 4; ++r) {
            float twv = tw_[r], tcv = tc_[r], dxv = dx_[r];
            if (!(twv > -INFINITY && tcv > -INFINITY && dxv > -INFINITY)) continue;
            int c = (int)dxv;

            // predictions
            float pw = rcpf(1.0f + __expf(-l0_[r]));
            float pc = rcpf(1.0f + __expf(-l1_[r])) * (float)(T_DIM - 1) + 5.0f;

            // reparameterized Beta params
            float ta = fmaf(tcv, twv, 1.0f);
            float tb = tcv - tcv * twv + 1.0f;
            float pa = fmaf(pc, pw, 1.0f);
            float pb = pc - pc * pw + 1.0f;
            float sp = tcv + 2.0f;   // ta+tb, >= 7
            float sq = pc + 2.0f;    // pa+pb, >= 7

            // shifted arguments (all >= 2 for Stirling, >= 3 for digamma)
            float yta = ta + 2.0f, ytb = tb + 2.0f;
            float ypa = pa + 1.0f, ypb = pb + 1.0f;

            float l_ta = __logf(yta), l_tb = __logf(ytb);
            float l_pa = __logf(ypa), l_pb = __logf(ypb);
            float l_sp = __logf(sp),  l_sq = __logf(sq);
            float u_ta = rcpf(yta), u_tb = rcpf(ytb);
            float u_pa = rcpf(ypa), u_pb = rcpf(ypb);
            float u_sp = rcpf(sp),  u_sq = rcpf(sq);

            // Stirling main terms: +lg(pa)+lg(pb)+lg(sp) -lg(ta)-lg(tb)-lg(sq)
            float st = stirl(ypa, l_pa, u_pa) + stirl(ypb, l_pb, u_pb)
                     + stirl(sp,  l_sp, u_sp) - stirl(yta, l_ta, u_ta)
                     - stirl(ytb, l_tb, u_tb) - stirl(sq,  l_sq, u_sq);

            // shift corrections folded into one log:
            // +ln(ta(ta+1)) + ln(tb(tb+1)) - ln(pa) - ln(pb)
            float qta = ta * (ta + 1.0f);   // reused for digamma shift
            float qtb = tb * (tb + 1.0f);
            float corr = __logf((qta * qtb) * rcpf(pa * pb));

            // digammas: psi(x) = psi(x+2) - (2x+1)/(x(x+1)) for ta,tb; sp direct
            float dta = digam(l_ta, u_ta) - (2.0f * ta + 1.0f) * rcpf(qta);
            float dtb = digam(l_tb, u_tb) - (2.0f * tb + 1.0f) * rcpf(qtb);
            float dsp = digam(l_sp, u_sp);

            float kl = st + corr
                     + (ta - pa) * dta + (tb - pb) * dtb + (sq - sp) * dsp;

            int li = (lt4 + r) * NCLS + c;
            atomicAdd(&lksum[li], kl);
            atomicAdd(&lcnt[li], 1.0f);
        }
    }
    __syncthreads();

    for (int i = threadIdx.x; i < TB * NCLS; i += THREADS) {
        float cv = lcnt[i];
        if (cv != 0.0f) {
            atomicAdd(&gcnt[t0 * NCLS + i], cv);
            atomicAdd(&gksum[t0 * NCLS + i], lksum[i]);
        }
    }
}

__global__ void kl_final(const float* __restrict__ gcnt,
                         const float* __restrict__ gksum,
                         float* __restrict__ out) {
    __shared__ float red[256];
    float s = 0.0f;
    for (int i = threadIdx.x; i < T_DIM * NCLS; i += 256) {
        float cv = gcnt[i];
        if (cv > 0.0f) s += gksum[i] / cv;
    }
    red[threadIdx.x] = s;
    __syncthreads();
    for (int off = 128; off > 0; off >>= 1) {
        if ((int)threadIdx.x < off) red[threadIdx.x] += red[threadIdx.x + off];
        __syncthreads();
    }
    if (threadIdx.x == 0) out[0] = red[0] / (float)(NCLS * T_DIM);
}

extern "C" void kernel_launch(void* const* d_in, const int* in_sizes, int n_in,
                              void* d_out, int out_size, void* d_ws, size_t ws_size,
                              hipStream_t stream) {
    const float* logits  = (const float*)d_in[0];  // [B,T,2] f32
    const float* targets = (const float*)d_in[1];  // [B,T,3] f32
    float* gcnt  = (float*)d_ws;                   // [T*3]
    float* gksum = gcnt + T_DIM * NCLS;            // [T*3]
    float* out   = (float*)d_out;

    kl_zero<<<(T_DIM * NCLS * 2 + 255) / 256, 256, 0, stream>>>((float*)d_ws);
    kl_partial<<<NT * NB, THREADS, 0, stream>>>(logits, targets, gcnt, gksum);
    kl_final<<<1, 256, 0, stream>>>(gcnt, gksum, out);
}

// Round 10
// 112.015 us; speedup vs baseline: 1.4540x; 1.2388x over previous
//
#include <hip/hip_runtime.h>
#include <math.h>

#define B_DIM 4096
#define T_DIM 1024
#define NCLS  3

#define NT (T_DIM / 64)        // 16 t-chunks (64 t per block, lane = t)
#define ROWS 8                 // b-rows per thread
#define WAVES 4                // waves per block
#define NBC (B_DIM / (WAVES * ROWS))  // 128 b-chunks
#define THREADS 256
#define LN2 0.69314718055994531f

__device__ __forceinline__ float rcpf(float x) { return __builtin_amdgcn_rcpf(x); }

__global__ void kl_zero(float* ws) {
    int i = blockIdx.x * 256 + threadIdx.x;
    if (i < T_DIM * NCLS * 2) ws[i] = 0.0f;
}

__global__ __launch_bounds__(THREADS)
void kl_partial(const float* __restrict__ logits,
                const float* __restrict__ targets,
                float* __restrict__ gcnt,
                float* __restrict__ gksum) {
    const int tchunk = blockIdx.x % NT;
    const int bchunk = blockIdx.x / NT;
    const int lane = threadIdx.x & 63;
    const int wv   = threadIdx.x >> 6;            // 0..3
    const int t    = tchunk * 64 + lane;
    const int b0   = bchunk * (WAVES * ROWS) + wv * ROWS;

    float k0 = 0.f, k1 = 0.f, k2 = 0.f;
    float n0 = 0.f, n1 = 0.f, n2 = 0.f;

    const size_t row0 = (size_t)b0 * T_DIM + t;
    const float* tgp = targets + row0 * 3;
    const float* lgp = logits + row0 * 2;

    float3 tg = *(const float3*)tgp;
    float2 lg = *(const float2*)lgp;

#pragma unroll
    for (int it = 0; it < ROWS; ++it) {
        float3 tgc = tg;
        float2 lgc = lg;
        if (it < ROWS - 1) {                       // prefetch next row
            tg = *(const float3*)(tgp + (size_t)(it + 1) * T_DIM * 3);
            lg = *(const float2*)(lgp + (size_t)(it + 1) * T_DIM * 2);
        }

        // branchless sanitize (padding rows are all -inf; valid tc in [5,30])
        const bool v = (tgc.y > 0.0f);
        const float vm  = v ? 1.0f : 0.0f;
        const float tw  = v ? tgc.x : 0.5f;
        const float tc  = v ? tgc.y : 5.0f;
        const float dxs = v ? tgc.z : 0.0f;

        // predictions
        const float pw = rcpf(1.0f + __expf(-lgc.x));
        const float pc = fmaf(rcpf(1.0f + __expf(-lgc.y)), (float)(T_DIM - 1), 5.0f);

        // Beta params
        const float ta = fmaf(tc, tw, 1.0f);
        const float tb = tc - tc * tw + 1.0f;
        const float pa = fmaf(pc, pw, 1.0f);
        const float pb = pc - pc * pw + 1.0f;
        const float sp = tc + 2.0f;               // ta+tb, >= 7
        const float sq = pc + 2.0f;               // pa+pb, >= 7

        // shifted args: Stirling needs >=2, digamma >=3
        const float yta = ta + 2.0f, ytb = tb + 2.0f;
        const float ypa = pa + 1.0f, ypb = pb + 1.0f;

        const float u_ta = rcpf(yta), u_tb = rcpf(ytb);
        const float u_pa = rcpf(ypa), u_pb = rcpf(ypb);
        const float u_sp = rcpf(sp),  u_sq = rcpf(sq);
        const float qta = ta * (ta + 1.0f);       // gamma-shift for ta by 2
        const float qtb = tb * (tb + 1.0f);
        const float rqta = rcpf(qta), rqtb = rcpf(qtb);

        // ---- folded log2 part ----
        // L = (pa+.5)lg2(ypa/yta) + (pb+.5)lg2(ypb/ytb) + (sq-.5)lg2(sp/sq)
        //   + lg2( qta*qtb / (pa*pb*yta*ytb) )
        const float lr_a = __log2f(ypa * u_ta);
        const float lr_b = __log2f(ypb * u_tb);
        const float lr_s = __log2f(sp * u_sq);
        const float lr_c = __log2f(qta * qtb * rcpf(pa * pb * yta * ytb));
        float L = fmaf(pa + 0.5f, lr_a,
                  fmaf(pb + 0.5f, lr_b,
                  fmaf(sq - 0.5f, lr_s, lr_c)));

        // ---- non-log remainder ----
        // Stirling u/12 sum (signs: +ypa +ypb +sp -yta -ytb -sq); -y terms sum to +2
        const float S = (u_pa + u_pb + u_sp) - (u_ta + u_tb + u_sq);

        // digamma remainders (series part minus ln): r(y) = -u/2 - u^2*(c1 - u^2*(c2 - u^2*c3))
        #define DGR(u) (-0.5f*(u) - (u)*(u)*(0.083333333333333f \
                        - (u)*(u)*(0.0083333333333333f - (u)*(u)*0.0039682539682540f)))
        const float rta = DGR(u_ta) - (2.0f * ta + 1.0f) * rqta;  // psi(ta) shift by 2
        const float rtb = DGR(u_tb) - (2.0f * tb + 1.0f) * rqtb;
        const float rsp = DGR(u_sp);
        #undef DGR

        float kl = fmaf(LN2, L, 2.0f) + S * 0.083333333333333f
                 + (ta - pa) * rta + (tb - pb) * rtb + (sq - sp) * rsp;

        // class masks (dx is exactly 0.0/1.0/2.0)
        const float m1 = (dxs == 1.0f) ? vm : 0.0f;
        const float m2 = (dxs == 2.0f) ? vm : 0.0f;
        const float m0 = vm - m1 - m2;
        k0 = fmaf(m0, kl, k0);  n0 += m0;
        k1 = fmaf(m1, kl, k1);  n1 += m1;
        k2 = fmaf(m2, kl, k2);  n2 += m2;
    }

    // block reduction: 4 waves share the same 64 t values
    __shared__ float rk[WAVES][64][NCLS];
    __shared__ float rn[WAVES][64][NCLS];
    rk[wv][lane][0] = k0; rk[wv][lane][1] = k1; rk[wv][lane][2] = k2;
    rn[wv][lane][0] = n0; rn[wv][lane][1] = n1; rn[wv][lane][2] = n2;
    __syncthreads();

    if (threadIdx.x < 64) {
        const int l = threadIdx.x;
        const int gt = tchunk * 64 + l;
#pragma unroll
        for (int c = 0; c < NCLS; ++c) {
            float ks = rk[0][l][c] + rk[1][l][c] + rk[2][l][c] + rk[3][l][c];
            float ns = rn[0][l][c] + rn[1][l][c] + rn[2][l][c] + rn[3][l][c];
            atomicAdd(&gksum[gt * NCLS + c], ks);
            atomicAdd(&gcnt[gt * NCLS + c], ns);
        }
    }
}

__global__ void kl_final(const float* __restrict__ gcnt,
                         const float* __restrict__ gksum,
                         float* __restrict__ out) {
    __shared__ float red[256];
    float s = 0.0f;
    for (int i = threadIdx.x; i < T_DIM * NCLS; i += 256) {
        float cv = gcnt[i];
        if (cv > 0.0f) s += gksum[i] * rcpf(cv);
    }
    red[threadIdx.x] = s;
    __syncthreads();
    for (int off = 128; off > 0; off >>= 1) {
        if ((int)threadIdx.x < off) red[threadIdx.x] += red[threadIdx.x + off];
        __syncthreads();
    }
    if (threadIdx.x == 0) out[0] = red[0] / (float)(NCLS * T_DIM);
}

extern "C" void kernel_launch(void* const* d_in, const int* in_sizes, int n_in,
                              void* d_out, int out_size, void* d_ws, size_t ws_size,
                              hipStream_t stream) {
    const float* logits  = (const float*)d_in[0];  // [B,T,2] f32
    const float* targets = (const float*)d_in[1];  // [B,T,3] f32
    float* gcnt  = (float*)d_ws;                   // [T*3]
    float* gksum = gcnt + T_DIM * NCLS;            // [T*3]
    float* out   = (float*)d_out;

    kl_zero<<<(T_DIM * NCLS * 2 + 255) / 256, 256, 0, stream>>>((float*)d_ws);
    kl_partial<<<NT * NBC, THREADS, 0, stream>>>(logits, targets, gcnt, gksum);
    kl_final<<<1, 256, 0, stream>>>(gcnt, gksum, out);
}